// Round 4
// baseline (95.439 us; speedup 1.0000x reference)
//
#include <hip/hip_runtime.h>

#define Oo    32
#define F2    4096
#define NBLKS 256            // pixel tiles of 16
#define SLOTS 512            // NBLKS * 2 sub-halves
#define NTOT  (32 * F2)      // 131072 elements per channel
#define PSTR  36             // h2 stride of a (q,pixel) row: 32 batches + 4 pad

typedef _Float16 h2 __attribute__((ext_vector_type(2)));

#if __has_builtin(__builtin_amdgcn_fdot2)
#define DOT2(a, b, c) __builtin_amdgcn_fdot2((a), (b), (c), false)
#else
__device__ __forceinline__ float DOT2(h2 a, h2 b, float c) {
    return c + (float)a.x * (float)b.x + (float)a.y * (float)b.y;
}
#endif

__device__ __forceinline__ h2 bc_h2(unsigned u) { return __builtin_bit_cast(h2, u); }
__device__ __forceinline__ h2 pack2(float a, float b) {
    h2 t; t.x = (_Float16)a; t.y = (_Float16)b; return t;
}

// Block: 512 threads = (sub:2 batch-half) x (og:16) x (f:16 pixels), grid 256.
// Thread owns acc[2][16]: 2 output channels (og, og+16) x 16 batches -> the
// batch loop is gone. Main loop: p-dimension in 4 chunks of 18; per chunk the
// patch slice lives in double-buffered LDS (layout [q][pixel][batch] h2,
// stride 36 -> 2-way bank aliasing = free) and the chunk's weights stream
// from HBM directly into registers, prefetched one full chunk (~1700 cy)
// ahead. 4 barriers total. BN partials reduced from registers at the end.
__global__ __launch_bounds__(512, 2) void svconv_kernel(
    const float* __restrict__ x, const float* __restrict__ wgt,
    const float* __restrict__ bias, float* __restrict__ y,
    float* __restrict__ psum, float* __restrict__ psumsq)
{
    __shared__ __align__(16) h2 pat[2][9 * 16 * PSTR];   // 2 x 5184 h2 = 41.5 KB

    const int tid = threadIdx.x;
    const int f   = tid & 15;
    const int og  = (tid >> 4) & 15;
    const int sub = tid >> 8;
    const int fb  = blockIdx.x * 16;
    const int col = fb + f;
    const int h   = fb >> 6;
    const int w0  = fb & 63;

    // gather role: thread = (batch gb, pixel gp)
    const int gb = tid >> 4;          // 0..31
    const int gp = tid & 15;          // 0..15
    const float* xrow = x + gb * 32768 + (h - 1) * 64 + (w0 + gp - 1);
    const bool mh0 = (h > 0), mh2 = (h < 63);
    const bool mw0 = (w0 + gp > 0), mw2 = (w0 + gp < 63);

    const int o0 = og, o1 = og + 16;
    const float* wp0 = wgt + (size_t)o0 * 72 * F2 + col;
    const float* wp1 = wgt + (size_t)o1 * 72 * F2 + col;
    const float bz0 = bias[o0 * F2 + col];
    const float bz1 = bias[o1 * F2 + col];

    float acc[2][16];
#pragma unroll
    for (int j = 0; j < 2; ++j)
#pragma unroll
        for (int k = 0; k < 16; ++k) acc[j][k] = 0.f;

    float xg[2][18];        // prefetched patch values (chunk parity)
    float wf[2][2][18];     // prefetched weights [parity][j][p-local]
    h2    w2h[2][9];        // packed weights for the chunk being computed

    // gather x element for global patch index p (i compile-time after unroll)
    auto gather = [&](int c, int i) -> float {
        const int cc = 2 * c + (i / 9);       // channel
        const int r  = i % 9;
        const int kh = r / 3, kw = r - kh * 3;
        const bool ok = (kh == 0 ? mh0 : (kh == 2 ? mh2 : true)) &&
                        (kw == 0 ? mw0 : (kw == 2 ? mw2 : true));
        return ok ? xrow[cc * 4096 + kh * 64 + kw] : 0.f;
    };

    auto issue = [&](int c) {
        const int s = c & 1;
#pragma unroll
        for (int i = 0; i < 18; ++i) xg[s][i] = gather(c, i);
#pragma unroll
        for (int i = 0; i < 18; ++i) {
            wf[s][0][i] = wp0[(18 * c + i) * F2];
            wf[s][1][i] = wp1[(18 * c + i) * F2];
        }
    };

    auto mat = [&](int c) {     // pack prefetched data: LDS patches + reg weights
        const int s = c & 1;
        h2* dst = &pat[s][0];
#pragma unroll
        for (int i = 0; i < 9; ++i)
            dst[(i * 16 + gp) * PSTR + gb] = pack2(xg[s][2 * i], xg[s][2 * i + 1]);
#pragma unroll
        for (int i = 0; i < 9; ++i) {
            w2h[0][i] = pack2(wf[s][0][2 * i], wf[s][0][2 * i + 1]);
            w2h[1][i] = pack2(wf[s][1][2 * i], wf[s][1][2 * i + 1]);
        }
    };

    auto compute = [&](int c) {
        const int s = c & 1;
        const unsigned* base = (const unsigned*)&pat[s][0];
#pragma unroll
        for (int q = 0; q < 9; ++q) {
            const uint4* row = (const uint4*)(base + (q * 16 + f) * PSTR + sub * 16);
#pragma unroll
            for (int m = 0; m < 4; ++m) {
                uint4 um = row[m];
                acc[0][4 * m + 0] = DOT2(w2h[0][q], bc_h2(um.x), acc[0][4 * m + 0]);
                acc[0][4 * m + 1] = DOT2(w2h[0][q], bc_h2(um.y), acc[0][4 * m + 1]);
                acc[0][4 * m + 2] = DOT2(w2h[0][q], bc_h2(um.z), acc[0][4 * m + 2]);
                acc[0][4 * m + 3] = DOT2(w2h[0][q], bc_h2(um.w), acc[0][4 * m + 3]);
                acc[1][4 * m + 0] = DOT2(w2h[1][q], bc_h2(um.x), acc[1][4 * m + 0]);
                acc[1][4 * m + 1] = DOT2(w2h[1][q], bc_h2(um.y), acc[1][4 * m + 1]);
                acc[1][4 * m + 2] = DOT2(w2h[1][q], bc_h2(um.z), acc[1][4 * m + 2]);
                acc[1][4 * m + 3] = DOT2(w2h[1][q], bc_h2(um.w), acc[1][4 * m + 3]);
            }
        }
    };

    // ---- pipeline: issue(c+1) is in flight while compute(c) runs ----
    issue(0);
    mat(0);
    issue(1);
    __syncthreads();

    compute(0);
    mat(1); issue(2);
    __syncthreads();

    compute(1);
    mat(2); issue(3);
    __syncthreads();

    compute(2);
    mat(3);
    __syncthreads();

    compute(3);

    // ---- y store + BN partials from registers ----
    float s0 = 0.f, ss0 = 0.f, s1 = 0.f, ss1 = 0.f;
#pragma unroll
    for (int k = 0; k < 16; ++k) {
        const int b = sub * 16 + k;
        float a0 = acc[0][k] + bz0;
        float a1 = acc[1][k] + bz1;
        y[(b * Oo + o0) * F2 + col] = a0;
        y[(b * Oo + o1) * F2 + col] = a1;
        s0 += a0; ss0 = fmaf(a0, a0, ss0);
        s1 += a1; ss1 = fmaf(a1, a1, ss1);
    }
#pragma unroll
    for (int d = 8; d >= 1; d >>= 1) {
        s0 += __shfl_down(s0, d, 16); ss0 += __shfl_down(ss0, d, 16);
        s1 += __shfl_down(s1, d, 16); ss1 += __shfl_down(ss1, d, 16);
    }
    if (f == 0) {
        const int slot = blockIdx.x * 2 + sub;
        psum[o0 * SLOTS + slot]   = s0;
        psumsq[o0 * SLOTS + slot] = ss0;
        psum[o1 * SLOTS + slot]   = s1;
        psumsq[o1 * SLOTS + slot] = ss1;
    }
}

__global__ __launch_bounds__(256) void bnstats_kernel(
    const float* __restrict__ psum, const float* __restrict__ psumsq,
    const float* __restrict__ gamma, const float* __restrict__ beta,
    float* __restrict__ scsh)
{
    const int o = blockIdx.x;
    const int t = threadIdx.x;
    float s  = psum[o * SLOTS + t]   + psum[o * SLOTS + t + 256];
    float ss = psumsq[o * SLOTS + t] + psumsq[o * SLOTS + t + 256];
#pragma unroll
    for (int d = 32; d >= 1; d >>= 1) {
        s  += __shfl_down(s, d, 64);
        ss += __shfl_down(ss, d, 64);
    }
    __shared__ float ls[4], lss[4];
    int wv = t >> 6, ln = t & 63;
    if (ln == 0) { ls[wv] = s; lss[wv] = ss; }
    __syncthreads();
    if (t == 0) {
        float S   = (ls[0] + ls[1]) + (ls[2] + ls[3]);
        float SS  = (lss[0] + lss[1]) + (lss[2] + lss[3]);
        float mean = S / (float)NTOT;
        float var  = SS / (float)NTOT - mean * mean;
        float rstd = rsqrtf(var + 1e-5f);
        float scl  = gamma[o] * rstd;
        scsh[o]      = scl;
        scsh[Oo + o] = beta[o] - mean * scl;
    }
}

__global__ __launch_bounds__(256) void bnapply_kernel(
    float* __restrict__ y, const float* __restrict__ scsh)
{
    int i = blockIdx.x * 256 + threadIdx.x;    // float4 index
    float4 v = ((const float4*)y)[i];
    int o = (i >> 10) & 31;                    // F2/4 = 1024 float4 per (b,o)
    float scl = scsh[o], sh = scsh[Oo + o];
    v.x = fmaf(v.x, scl, sh);
    v.y = fmaf(v.y, scl, sh);
    v.z = fmaf(v.z, scl, sh);
    v.w = fmaf(v.w, scl, sh);
    ((float4*)y)[i] = v;
}

extern "C" void kernel_launch(void* const* d_in, const int* in_sizes, int n_in,
                              void* d_out, int out_size, void* d_ws, size_t ws_size,
                              hipStream_t stream)
{
    const float* x     = (const float*)d_in[0];
    const float* wgt   = (const float*)d_in[1];
    const float* bias  = (const float*)d_in[2];
    const float* gamma = (const float*)d_in[3];
    const float* beta  = (const float*)d_in[4];
    float* y = (float*)d_out;

    float* psum   = (float*)d_ws;               // [Oo][SLOTS]
    float* psumsq = psum + Oo * SLOTS;          // [Oo][SLOTS]
    float* scsh   = psumsq + Oo * SLOTS;        // [2][Oo]

    svconv_kernel<<<NBLKS, 512, 0, stream>>>(x, wgt, bias, y, psum, psumsq);
    bnstats_kernel<<<Oo, 256, 0, stream>>>(psum, psumsq, gamma, beta, scsh);
    bnapply_kernel<<<NTOT * Oo / 4 / 256, 256, 0, stream>>>(y, scsh);
}

// Round 5
// 75.017 us; speedup vs baseline: 1.2722x; 1.2722x over previous
//
#include <hip/hip_runtime.h>

#define Oo   32
#define F2   4096
#define NB   256             // grid: 256 pixel tiles of 16
#define NTOT (32 * F2)
#define STR  36              // padded inner stride (h2 units)
#define PATW 5184            // patW base (h2 idx): pat = 9*16*36 = 5184

typedef _Float16 h2 __attribute__((ext_vector_type(2)));

#if __has_builtin(__builtin_amdgcn_fdot2)
#define DOT2(a, b, c) __builtin_amdgcn_fdot2((a), (b), (c), false)
#else
__device__ __forceinline__ float DOT2(h2 a, h2 b, float c) {
    return c + (float)a.x * (float)b.x + (float)a.y * (float)b.y;
}
#endif

__device__ __forceinline__ unsigned pkh2(float a, float b) {
    h2 t; t.x = (_Float16)a; t.y = (_Float16)b;
    return __builtin_bit_cast(unsigned, t);
}
__device__ __forceinline__ h2 bch2(unsigned u) { return __builtin_bit_cast(h2, u); }

// Block: 1024 thr = (bq:8) x (og:8) x (f:16), grid 256 (16-pixel tiles).
// Thread: 4 o's x 4 batches x 1 pixel -> acc[4][4] (16 VGPRs, no spill).
// p-dim in 4 chunks of 18 (= 2 channels); per chunk both the weight slice and
// the patch slice are staged in ONE 43.5KB LDS buffer as f16 p-pairs
// (padded stride 36 -> <=2-way bank conflicts, 16B-aligned b128 reads).
// Weights: coalesced float4, each 64B line read once chip-wide. Global loads
// for chunk c+1 issue before compute(c); LDS writes sit between 2 barriers.
__global__ __launch_bounds__(1024, 4) void svconv_kernel(
    const float* __restrict__ x, const float* __restrict__ wgt,
    const float* __restrict__ bias, float* __restrict__ y,
    float* __restrict__ psum, float* __restrict__ psumsq)
{
    __shared__ __align__(16) unsigned lds[2 * PATW];   // pat[0..5183], patW[5184..]

    const int tid = threadIdx.x;
    const int f   = tid & 15;
    const int og  = (tid >> 4) & 7;
    const int bq  = tid >> 7;
    const int fb  = blockIdx.x * 16;
    const int col = fb + f;
    const int h   = fb >> 6;
    const int w0  = fb & 63;

    // ---- x-gather slots: s = (pq*32 + b)*16 + f_, 4608 slots, 2 loads each ----
    int xo0[5], xo1[5], xl[5];
#pragma unroll
    for (int k = 0; k < 5; ++k) {
        int s = tid + k * 1024;
        if (s < 4608) {
            int f_ = s & 15, b_ = (s >> 4) & 31, pq = s >> 9;
            int p0 = 2 * pq, p1 = 2 * pq + 1;
            int cc0 = p0 / 9, r0 = p0 % 9, kh0 = r0 / 3, kw0 = r0 % 3;
            int cc1 = p1 / 9, r1 = p1 % 9, kh1 = r1 / 3, kw1 = r1 % 3;
            int gh0 = h - 1 + kh0, gw0 = w0 + f_ - 1 + kw0;
            int gh1 = h - 1 + kh1, gw1 = w0 + f_ - 1 + kw1;
            xo0[k] = ((unsigned)gh0 < 64u && (unsigned)gw0 < 64u)
                         ? b_ * 32768 + cc0 * 4096 + gh0 * 64 + gw0 : -1;
            xo1[k] = ((unsigned)gh1 < 64u && (unsigned)gw1 < 64u)
                         ? b_ * 32768 + cc1 * 4096 + gh1 * 64 + gw1 : -1;
            xl[k]  = (pq * 16 + f_) * STR + b_;
        } else { xo0[k] = -1; xo1[k] = -1; xl[k] = -1; }
    }

    // ---- weight slots: s = o*36 + pq*4 + quad, 1152 slots, 2 float4 each ----
    int  wo_[2], wl_[2];
    bool wv_[2];
#pragma unroll
    for (int k = 0; k < 2; ++k) {
        int s = tid + k * 1024;
        wv_[k] = (s < 1152);
        int o_ = s / 36, rm = s % 36, pq = rm >> 2, quad = rm & 3;
        if (!wv_[k]) { o_ = 0; pq = 0; quad = 0; }
        wo_[k] = (o_ * 72 + 2 * pq) * F2 + fb + quad * 4;
        wl_[k] = PATW + (pq * 16 + quad * 4) * STR + o_;
    }

    float bz[4];
#pragma unroll
    for (int j = 0; j < 4; ++j) bz[j] = bias[(og * 4 + j) * F2 + col];

    float acc[4][4];
#pragma unroll
    for (int j = 0; j < 4; ++j)
#pragma unroll
        for (int k = 0; k < 4; ++k) acc[j][k] = 0.f;

    float  xf0[5], xf1[5];
    float4 wA[2], wB[2];

    auto LOAD = [&](int c) {          // issue global loads for chunk c
#pragma unroll
        for (int k = 0; k < 5; ++k) {
            xf0[k] = (xo0[k] >= 0) ? x[xo0[k] + c * 8192] : 0.f;
            xf1[k] = (xo1[k] >= 0) ? x[xo1[k] + c * 8192] : 0.f;
        }
#pragma unroll
        for (int k = 0; k < 2; ++k)
            if (wv_[k]) {
                wA[k] = *(const float4*)(wgt + wo_[k] + c * 73728);
                wB[k] = *(const float4*)(wgt + wo_[k] + F2 + c * 73728);
            }
    };
    auto WRITE = [&]() {              // pack prefetched data into LDS
#pragma unroll
        for (int k = 0; k < 5; ++k)
            if (xl[k] >= 0) lds[xl[k]] = pkh2(xf0[k], xf1[k]);
#pragma unroll
        for (int k = 0; k < 2; ++k)
            if (wv_[k]) {
                lds[wl_[k]]           = pkh2(wA[k].x, wB[k].x);
                lds[wl_[k] + STR]     = pkh2(wA[k].y, wB[k].y);
                lds[wl_[k] + 2 * STR] = pkh2(wA[k].z, wB[k].z);
                lds[wl_[k] + 3 * STR] = pkh2(wA[k].w, wB[k].w);
            }
    };
    const int fo = f * STR;
    auto COMPUTE = [&]() {
#pragma unroll
        for (int pq = 0; pq < 9; ++pq) {
            uint4 wu = *(const uint4*)(lds + PATW + pq * 576 + fo + og * 4);
            uint4 pu = *(const uint4*)(lds + pq * 576 + fo + bq * 4);
            unsigned wq[4] = {wu.x, wu.y, wu.z, wu.w};
#pragma unroll
            for (int j = 0; j < 4; ++j) {
                h2 w = bch2(wq[j]);
                acc[j][0] = DOT2(w, bch2(pu.x), acc[j][0]);
                acc[j][1] = DOT2(w, bch2(pu.y), acc[j][1]);
                acc[j][2] = DOT2(w, bch2(pu.z), acc[j][2]);
                acc[j][3] = DOT2(w, bch2(pu.w), acc[j][3]);
            }
        }
    };

    // ---- pipeline: loads(c+1) in flight during compute(c) ----
    LOAD(0); WRITE(); __syncthreads();
    LOAD(1); COMPUTE(); __syncthreads(); WRITE(); __syncthreads();
    LOAD(2); COMPUTE(); __syncthreads(); WRITE(); __syncthreads();
    LOAD(3); COMPUTE(); __syncthreads(); WRITE(); __syncthreads();
    COMPUTE();

    // ---- epilogue: y store + BN partials ----
    float s[4], ss[4];
#pragma unroll
    for (int j = 0; j < 4; ++j) {
        s[j] = 0.f; ss[j] = 0.f;
#pragma unroll
        for (int k = 0; k < 4; ++k) {
            float a = acc[j][k] + bz[j];
            y[((bq * 4 + k) * Oo + og * 4 + j) * F2 + col] = a;
            s[j] += a; ss[j] = fmaf(a, a, ss[j]);
        }
    }
#pragma unroll
    for (int j = 0; j < 4; ++j)
#pragma unroll
        for (int d = 8; d >= 1; d >>= 1) {
            s[j]  += __shfl_down(s[j],  d, 16);
            ss[j] += __shfl_down(ss[j], d, 16);
        }

    __syncthreads();                       // LDS reads done; reuse as scratch
    float* scp  = (float*)lds;             // [32][8]
    float* sspp = scp + 256;               // [32][8]
    if (f == 0) {
#pragma unroll
        for (int j = 0; j < 4; ++j) {
            scp[(og * 4 + j) * 8 + bq]  = s[j];
            sspp[(og * 4 + j) * 8 + bq] = ss[j];
        }
    }
    __syncthreads();
    if (tid < 256) {
        int o = tid >> 3, q = tid & 7;
        float v  = scp[o * 8 + q];
        float vv = sspp[o * 8 + q];
#pragma unroll
        for (int d = 4; d >= 1; d >>= 1) {
            v  += __shfl_down(v,  d, 8);
            vv += __shfl_down(vv, d, 8);
        }
        if (q == 0) {
            psum[o * NB + blockIdx.x]   = v;
            psumsq[o * NB + blockIdx.x] = vv;
        }
    }
}

__global__ __launch_bounds__(256) void bnstats_kernel(
    const float* __restrict__ psum, const float* __restrict__ psumsq,
    const float* __restrict__ gamma, const float* __restrict__ beta,
    float* __restrict__ scsh)
{
    const int o = blockIdx.x;
    const int t = threadIdx.x;
    float s  = psum[o * NB + t];
    float ss = psumsq[o * NB + t];
#pragma unroll
    for (int d = 32; d >= 1; d >>= 1) {
        s  += __shfl_down(s, d, 64);
        ss += __shfl_down(ss, d, 64);
    }
    __shared__ float ls[4], lss[4];
    int wv = t >> 6, ln = t & 63;
    if (ln == 0) { ls[wv] = s; lss[wv] = ss; }
    __syncthreads();
    if (t == 0) {
        float S   = (ls[0] + ls[1]) + (ls[2] + ls[3]);
        float SS  = (lss[0] + lss[1]) + (lss[2] + lss[3]);
        float mean = S / (float)NTOT;
        float var  = SS / (float)NTOT - mean * mean;
        float rstd = rsqrtf(var + 1e-5f);
        float scl  = gamma[o] * rstd;
        scsh[o]      = scl;
        scsh[Oo + o] = beta[o] - mean * scl;
    }
}

__global__ __launch_bounds__(256) void bnapply_kernel(
    float* __restrict__ y, const float* __restrict__ scsh)
{
    int i = blockIdx.x * 256 + threadIdx.x;    // float4 index
    float4 v = ((const float4*)y)[i];
    int o = (i >> 10) & 31;                    // F2/4 = 1024 float4 per (b,o)
    float scl = scsh[o], sh = scsh[Oo + o];
    v.x = fmaf(v.x, scl, sh);
    v.y = fmaf(v.y, scl, sh);
    v.z = fmaf(v.z, scl, sh);
    v.w = fmaf(v.w, scl, sh);
    ((float4*)y)[i] = v;
}

extern "C" void kernel_launch(void* const* d_in, const int* in_sizes, int n_in,
                              void* d_out, int out_size, void* d_ws, size_t ws_size,
                              hipStream_t stream)
{
    const float* x     = (const float*)d_in[0];
    const float* wgt   = (const float*)d_in[1];
    const float* bias  = (const float*)d_in[2];
    const float* gamma = (const float*)d_in[3];
    const float* beta  = (const float*)d_in[4];
    float* y = (float*)d_out;

    float* psum   = (float*)d_ws;               // [Oo][NB]
    float* psumsq = psum + Oo * NB;             // [Oo][NB]
    float* scsh   = psumsq + Oo * NB;           // [2][Oo]

    svconv_kernel<<<NB, 1024, 0, stream>>>(x, wgt, bias, y, psum, psumsq);
    bnstats_kernel<<<Oo, 256, 0, stream>>>(psum, psumsq, gamma, beta, scsh);
    bnapply_kernel<<<NTOT * Oo / 4 / 256, 256, 0, stream>>>(y, scsh);
}